// Round 3
// baseline (2853.324 us; speedup 1.0000x reference)
//
#include <hip/hip_runtime.h>
#include <hip/hip_bf16.h>

typedef __bf16 bf16_t;
typedef bf16_t bf16x8 __attribute__((ext_vector_type(8)));
typedef float floatx4 __attribute__((ext_vector_type(4)));

#define BBS 2
#define SEQ 2048
#define DIM 1024
#define NH 16
#define HD 64
#define DFF_ 4096
#define NT (BBS*SEQ)

// ---------------------------------------------------------------------------
// Generic 64x64-tile batched GEMM: C = scale*(A @ B(^T)) + bias, optional relu.
// A: [M,K] row-major, f32 (AF32) or bf16. B: [K,N] (ldb), f32 (BF32) or bf16;
// or BT: [N,K] bf16 only. C: f32 or bf16. Staging converts f32->bf16 into LDS.
// mfma_f32_16x16x32_bf16; 4 waves, each 16 rows x 64 cols of the tile.
// ---------------------------------------------------------------------------
template<bool AF32, bool BF32, bool BT, bool OUTF32, bool RELU, bool BIAS>
__global__ __launch_bounds__(256) void gemm64(
    const void* __restrict__ Av, const void* __restrict__ Bv,
    const float* __restrict__ bias, void* __restrict__ Cout,
    int M, int N, int K, int lda, int ldb, int ldc,
    int batchH, long long sAb, long long sAh, long long sBb, long long sBh,
    long long sCb, long long sCh, float scale)
{
    int z = blockIdx.z;
    int zb = z / batchH, zh = z - zb * batchH;
    long long aoff = zb * sAb + zh * sAh;
    long long boff = zb * sBb + zh * sBh;
    long long coff = zb * sCb + zh * sCh;
    const bf16_t* A16 = (const bf16_t*)Av + aoff;
    const float*  A32 = (const float*)Av + aoff;
    const bf16_t* B16 = (const bf16_t*)Bv + boff;
    const float*  B32 = (const float*)Bv + boff;

    int tile_n = blockIdx.x * 64;
    int tile_m = blockIdx.y * 64;

    __shared__ __align__(16) bf16_t Alds[64 * 72];
    __shared__ __align__(16) bf16_t Blds[64 * 72];

    int tid  = threadIdx.x;
    int wave = tid >> 6;
    int lane = tid & 63;
    int lm = lane & 15;   // A row / B col / C col
    int lq = lane >> 4;   // quad

    floatx4 acc[4];
    #pragma unroll
    for (int i = 0; i < 4; ++i) acc[i] = (floatx4){0.f, 0.f, 0.f, 0.f};

    int s_row  = tid >> 2;          // 0..63
    int s_koff = (tid & 3) * 16;    // 0,16,32,48
    int nb_k   = tid >> 3;          // 0..31
    int nb_noff= (tid & 7) * 8;     // 0..56

    int nkt = K >> 6;
    for (int kt = 0; kt < nkt; ++kt) {
        int k0 = kt << 6;
        if constexpr (AF32) {       // A f32 [64r][64k] -> bf16 Alds[row*72+k]
            const float* src = A32 + (long long)(tile_m + s_row) * lda + (k0 + s_koff);
            float4 f0 = ((const float4*)src)[0];
            float4 f1 = ((const float4*)src)[1];
            float4 f2 = ((const float4*)src)[2];
            float4 f3 = ((const float4*)src)[3];
            bf16x8 h0, h1;
            h0[0]=(bf16_t)f0.x; h0[1]=(bf16_t)f0.y; h0[2]=(bf16_t)f0.z; h0[3]=(bf16_t)f0.w;
            h0[4]=(bf16_t)f1.x; h0[5]=(bf16_t)f1.y; h0[6]=(bf16_t)f1.z; h0[7]=(bf16_t)f1.w;
            h1[0]=(bf16_t)f2.x; h1[1]=(bf16_t)f2.y; h1[2]=(bf16_t)f2.z; h1[3]=(bf16_t)f2.w;
            h1[4]=(bf16_t)f3.x; h1[5]=(bf16_t)f3.y; h1[6]=(bf16_t)f3.z; h1[7]=(bf16_t)f3.w;
            *(bf16x8*)&Alds[s_row * 72 + s_koff]     = h0;
            *(bf16x8*)&Alds[s_row * 72 + s_koff + 8] = h1;
        } else {
            const bf16_t* src = A16 + (long long)(tile_m + s_row) * lda + (k0 + s_koff);
            *(uint4*)&Alds[s_row * 72 + s_koff]     = *(const uint4*)src;
            *(uint4*)&Alds[s_row * 72 + s_koff + 8] = *(const uint4*)(src + 8);
        }
        if constexpr (BT) {   // B bf16 [N,K]: direct copy -> Blds[n*72 + k]
            const bf16_t* src = B16 + (long long)(tile_n + s_row) * ldb + (k0 + s_koff);
            *(uint4*)&Blds[s_row * 72 + s_koff]     = *(const uint4*)src;
            *(uint4*)&Blds[s_row * 72 + s_koff + 8] = *(const uint4*)(src + 8);
        } else if constexpr (BF32) {  // B f32 [K,N]: transpose+convert
            #pragma unroll
            for (int kk = 0; kk < 64; kk += 32) {
                int k = kk + nb_k;
                const float* src = B32 + (long long)(k0 + k) * ldb + (tile_n + nb_noff);
                float4 f0 = ((const float4*)src)[0];
                float4 f1 = ((const float4*)src)[1];
                Blds[(nb_noff + 0) * 72 + k] = (bf16_t)f0.x;
                Blds[(nb_noff + 1) * 72 + k] = (bf16_t)f0.y;
                Blds[(nb_noff + 2) * 72 + k] = (bf16_t)f0.z;
                Blds[(nb_noff + 3) * 72 + k] = (bf16_t)f0.w;
                Blds[(nb_noff + 4) * 72 + k] = (bf16_t)f1.x;
                Blds[(nb_noff + 5) * 72 + k] = (bf16_t)f1.y;
                Blds[(nb_noff + 6) * 72 + k] = (bf16_t)f1.z;
                Blds[(nb_noff + 7) * 72 + k] = (bf16_t)f1.w;
            }
        } else {              // B bf16 [K,N]: transpose into n-major
            #pragma unroll
            for (int kk = 0; kk < 64; kk += 32) {
                int k = kk + nb_k;
                bf16x8 v = *(const bf16x8*)(B16 + (long long)(k0 + k) * ldb + (tile_n + nb_noff));
                #pragma unroll
                for (int j = 0; j < 8; ++j)
                    Blds[(nb_noff + j) * 72 + k] = v[j];
            }
        }
        __syncthreads();
        #pragma unroll
        for (int ks = 0; ks < 2; ++ks) {
            bf16x8 af = *(const bf16x8*)&Alds[(wave * 16 + lm) * 72 + ks * 32 + lq * 8];
            #pragma unroll
            for (int nt = 0; nt < 4; ++nt) {
                bf16x8 bfr = *(const bf16x8*)&Blds[(nt * 16 + lm) * 72 + ks * 32 + lq * 8];
                acc[nt] = __builtin_amdgcn_mfma_f32_16x16x32_bf16(af, bfr, acc[nt], 0, 0, 0);
            }
        }
        __syncthreads();
    }

    // epilogue: C/D layout col=lane&15, row=(lane>>4)*4+reg
    #pragma unroll
    for (int nt = 0; nt < 4; ++nt) {
        int col = tile_n + nt * 16 + lm;
        float bv = 0.f;
        if constexpr (BIAS) bv = bias[col];
        #pragma unroll
        for (int r = 0; r < 4; ++r) {
            int row = tile_m + wave * 16 + lq * 4 + r;
            float v = acc[nt][r] * scale + bv;
            if constexpr (RELU) v = fmaxf(v, 0.f);
            long long idx = coff + (long long)row * ldc + col;
            if constexpr (OUTF32) ((float*)Cout)[idx] = v;
            else                  ((bf16_t*)Cout)[idx] = (bf16_t)v;
        }
    }
}

// ---------------------------------------------------------------------------
// In-place row softmax over f32 [rows x 2048]; one wave per row.
// ---------------------------------------------------------------------------
__global__ __launch_bounds__(256) void softmax_f32(float* __restrict__ p)
{
    int row  = blockIdx.x * 4 + (threadIdx.x >> 6);
    int lane = threadIdx.x & 63;
    float* pr = p + (long long)row * SEQ;
    float v[32];
    float mx = -3.4e38f;
    #pragma unroll
    for (int it = 0; it < 8; ++it) {
        float4 c = *(const float4*)(pr + it * 256 + lane * 4);
        v[it*4+0] = c.x; v[it*4+1] = c.y; v[it*4+2] = c.z; v[it*4+3] = c.w;
        mx = fmaxf(mx, fmaxf(fmaxf(c.x, c.y), fmaxf(c.z, c.w)));
    }
    for (int off = 32; off; off >>= 1) mx = fmaxf(mx, __shfl_xor(mx, off));
    float s = 0.f;
    #pragma unroll
    for (int i = 0; i < 32; ++i) { v[i] = __expf(v[i] - mx); s += v[i]; }
    for (int off = 32; off; off >>= 1) s += __shfl_xor(s, off);
    float inv = 1.f / s;
    #pragma unroll
    for (int it = 0; it < 8; ++it) {
        float4 c;
        c.x = v[it*4+0]*inv; c.y = v[it*4+1]*inv; c.z = v[it*4+2]*inv; c.w = v[it*4+3]*inv;
        *(float4*)(pr + it * 256 + lane * 4) = c;
    }
}

// ---------------------------------------------------------------------------
// Sliding-window attention (|i-j| < 128), online softmax, one wave per (b,h,i).
// lane = head dim d. Q,K,V are bf16 ws buffers. Never materializes probs.
// ---------------------------------------------------------------------------
__global__ __launch_bounds__(256) void sw_attn_kernel(
    const bf16_t* __restrict__ Q, const bf16_t* __restrict__ K,
    const bf16_t* __restrict__ V, bf16_t* __restrict__ ctx)
{
    int gw   = blockIdx.x * 4 + (threadIdx.x >> 6);
    int lane = threadIdx.x & 63;
    int i  = gw & (SEQ - 1);
    int bh = gw >> 11;
    int h  = bh & (NH - 1);
    int b  = bh >> 4;
    long long rowbase = ((long long)(b * SEQ + i)) * DIM + h * HD;
    float q = (float)Q[rowbase + lane];
    const bf16_t* Kb = K + (long long)b * SEQ * DIM + h * HD;
    const bf16_t* Vb = V + (long long)b * SEQ * DIM + h * HD;
    int jlo = i - 127; if (jlo < 0) jlo = 0;
    int jhi = i + 127; if (jhi > SEQ - 1) jhi = SEQ - 1;
    float m = -3.4e38f, l = 0.f, acc = 0.f;
    for (int j = jlo; j <= jhi; ++j) {
        float kd = (float)Kb[(long long)j * DIM + lane];
        float part = q * kd;
        for (int off = 32; off; off >>= 1) part += __shfl_xor(part, off);
        float sc = part * 0.125f;
        float mn = fmaxf(m, sc);
        float corr = __expf(m - mn);
        float pp   = __expf(sc - mn);
        float vd = (float)Vb[(long long)j * DIM + lane];
        l   = l * corr + pp;
        acc = acc * corr + pp * vd;
        m = mn;
    }
    ctx[rowbase + lane] = (bf16_t)(acc / l);
}

// ---------------------------------------------------------------------------
// full_out = LN(o1+x)*g1+be1 ; sw_out = LN(o2+x)*g2+be2 ; sum -> bf16 + f32
// One block per token. All f32 I/O except sum_bf.
// ---------------------------------------------------------------------------
__global__ __launch_bounds__(256) void add_ln2_kernel(
    const float* __restrict__ o1, const float* __restrict__ o2,
    const float* __restrict__ x,
    const float* __restrict__ g1, const float* __restrict__ be1,
    const float* __restrict__ g2, const float* __restrict__ be2,
    bf16_t* __restrict__ sum_bf, float* __restrict__ sum_f)
{
    __shared__ float red[8];
    int t = blockIdx.x, tid = threadIdx.x;
    long long base = (long long)t * DIM;
    float a[4], b[4];
    float s1 = 0.f, s2 = 0.f;
    #pragma unroll
    for (int k = 0; k < 4; ++k) {
        int c = tid + k * 256;
        float xv = x[base + c];
        a[k] = o1[base + c] + xv;
        b[k] = o2[base + c] + xv;
        s1 += a[k]; s2 += b[k];
    }
    for (int off = 32; off; off >>= 1) { s1 += __shfl_xor(s1, off); s2 += __shfl_xor(s2, off); }
    if ((tid & 63) == 0) { red[tid >> 6] = s1; red[(tid >> 6) + 4] = s2; }
    __syncthreads();
    float m1 = (red[0] + red[1] + red[2] + red[3]) * (1.f / DIM);
    float m2 = (red[4] + red[5] + red[6] + red[7]) * (1.f / DIM);
    __syncthreads();
    float v1 = 0.f, v2 = 0.f;
    #pragma unroll
    for (int k = 0; k < 4; ++k) {
        float d1 = a[k] - m1, d2 = b[k] - m2;
        v1 += d1 * d1; v2 += d2 * d2;
    }
    for (int off = 32; off; off >>= 1) { v1 += __shfl_xor(v1, off); v2 += __shfl_xor(v2, off); }
    if ((tid & 63) == 0) { red[tid >> 6] = v1; red[(tid >> 6) + 4] = v2; }
    __syncthreads();
    v1 = (red[0] + red[1] + red[2] + red[3]) * (1.f / DIM);
    v2 = (red[4] + red[5] + red[6] + red[7]) * (1.f / DIM);
    float i1 = rsqrtf(v1 + 1e-5f), i2 = rsqrtf(v2 + 1e-5f);
    #pragma unroll
    for (int k = 0; k < 4; ++k) {
        int c = tid + k * 256;
        float va = (a[k] - m1) * i1 * g1[c] + be1[c];
        float vb = (b[k] - m2) * i2 * g2[c] + be2[c];
        float s  = va + vb;
        sum_f[base + c]  = s;
        sum_bf[base + c] = (bf16_t)s;
    }
}

// enc = LN(ffn_out + sum)*g3+be3 -> f32 out
__global__ __launch_bounds__(256) void final_ln_kernel(
    const float* __restrict__ ffn, const float* __restrict__ res,
    const float* __restrict__ g, const float* __restrict__ be,
    float* __restrict__ out)
{
    __shared__ float red[4];
    int t = blockIdx.x, tid = threadIdx.x;
    long long base = (long long)t * DIM;
    float a[4]; float s = 0.f;
    #pragma unroll
    for (int k = 0; k < 4; ++k) {
        int c = tid + k * 256;
        a[k] = ffn[base + c] + res[base + c];
        s += a[k];
    }
    for (int off = 32; off; off >>= 1) s += __shfl_xor(s, off);
    if ((tid & 63) == 0) red[tid >> 6] = s;
    __syncthreads();
    float m = (red[0] + red[1] + red[2] + red[3]) * (1.f / DIM);
    __syncthreads();
    float v = 0.f;
    #pragma unroll
    for (int k = 0; k < 4; ++k) { float d = a[k] - m; v += d * d; }
    for (int off = 32; off; off >>= 1) v += __shfl_xor(v, off);
    if ((tid & 63) == 0) red[tid >> 6] = v;
    __syncthreads();
    v = (red[0] + red[1] + red[2] + red[3]) * (1.f / DIM);
    float inv = rsqrtf(v + 1e-5f);
    #pragma unroll
    for (int k = 0; k < 4; ++k) {
        int c = tid + k * 256;
        out[base + c] = (a[k] - m) * inv * g[c] + be[c];
    }
}

extern "C" void kernel_launch(void* const* d_in, const int* in_sizes, int n_in,
                              void* d_out, int out_size, void* d_ws, size_t ws_size,
                              hipStream_t stream)
{
    const float* x   = (const float*)d_in[0];
    const float* wq1 = (const float*)d_in[1];
    const float* bq1 = (const float*)d_in[2];
    const float* wk1 = (const float*)d_in[3];
    const float* bk1 = (const float*)d_in[4];
    const float* wv1 = (const float*)d_in[5];
    const float* bv1 = (const float*)d_in[6];
    const float* wo1 = (const float*)d_in[7];
    const float* bo1 = (const float*)d_in[8];
    const float* g1  = (const float*)d_in[9];
    const float* be1 = (const float*)d_in[10];
    const float* wq2 = (const float*)d_in[11];
    const float* bq2 = (const float*)d_in[12];
    const float* wk2 = (const float*)d_in[13];
    const float* bk2 = (const float*)d_in[14];
    const float* wv2 = (const float*)d_in[15];
    const float* bv2 = (const float*)d_in[16];
    const float* wo2 = (const float*)d_in[17];
    const float* bo2 = (const float*)d_in[18];
    const float* g2  = (const float*)d_in[19];
    const float* be2 = (const float*)d_in[20];
    const float* wc1 = (const float*)d_in[21];
    const float* bc1 = (const float*)d_in[22];
    const float* wc2 = (const float*)d_in[23];
    const float* bc2 = (const float*)d_in[24];
    const float* g3  = (const float*)d_in[25];
    const float* be3 = (const float*)d_in[26];

    float* enc_out  = (float*)d_out;
    float* attn_out = enc_out + (long long)NT * DIM;    // [B,H,S,S] f32

    // Workspace (88 MB peak, lifetime-aliased):
    const size_t NTD = (size_t)NT * DIM;                // 4194304
    bf16_t* qb = (bf16_t*)d_ws;            // 8MB  Q (bf16)
    bf16_t* kb = qb + NTD;                 // 8MB  K
    bf16_t* vb = kb + NTD;                 // 8MB  V
    bf16_t* cb = vb + NTD;                 // 8MB  ctx
    float*  o1 = (float*)(cb + NTD);       // 16MB o1 f32 -> later ffo
    float*  o2 = o1 + NTD;                 // 16MB o2 f32
    bf16_t* sumbf = (bf16_t*)(o2 + NTD);   // 8MB  sum bf16 (FFN input)
    float*  sumf  = (float*)(sumbf + NTD); // 16MB sum f32 (residual)
    bf16_t* hbuf = qb;                     // [NT,DFF] bf16 = 32MB (qb..cb dead)
    float*  ffo  = o1;                     // [NT,DIM] f32 (o1 dead after LN2)

    dim3 blk(256);
    const long long SD = (long long)SEQ * DIM;          // per-batch token stride
    const long long SS = (long long)SEQ * SEQ;

    // ---- sliding-window branch first (its QKV buffers are reused later) ----
    gemm64<true,true,false,false,false,true><<<dim3(16,64,1),blk,0,stream>>>(x, wq2, bq2, qb, NT,DIM,DIM, DIM,DIM,DIM, 1, 0,0,0,0,0,0, 1.f);
    gemm64<true,true,false,false,false,true><<<dim3(16,64,1),blk,0,stream>>>(x, wk2, bk2, kb, NT,DIM,DIM, DIM,DIM,DIM, 1, 0,0,0,0,0,0, 1.f);
    gemm64<true,true,false,false,false,true><<<dim3(16,64,1),blk,0,stream>>>(x, wv2, bv2, vb, NT,DIM,DIM, DIM,DIM,DIM, 1, 0,0,0,0,0,0, 1.f);
    sw_attn_kernel<<<dim3((BBS*NH*SEQ)/4),blk,0,stream>>>(qb, kb, vb, cb);
    gemm64<false,true,false,true,false,true><<<dim3(16,64,1),blk,0,stream>>>(cb, wo2, bo2, o2, NT,DIM,DIM, DIM,DIM,DIM, 1, 0,0,0,0,0,0, 1.f);

    // ---- full-attention branch (reusing qb/kb/vb/cb) ----
    gemm64<true,true,false,false,false,true><<<dim3(16,64,1),blk,0,stream>>>(x, wq1, bq1, qb, NT,DIM,DIM, DIM,DIM,DIM, 1, 0,0,0,0,0,0, 1.f);
    gemm64<true,true,false,false,false,true><<<dim3(16,64,1),blk,0,stream>>>(x, wk1, bk1, kb, NT,DIM,DIM, DIM,DIM,DIM, 1, 0,0,0,0,0,0, 1.f);
    gemm64<true,true,false,false,false,true><<<dim3(16,64,1),blk,0,stream>>>(x, wv1, bv1, vb, NT,DIM,DIM, DIM,DIM,DIM, 1, 0,0,0,0,0,0, 1.f);

    // scores: per (b,h): Q_head @ K_head^T / 8 -> f32 attn region of d_out
    gemm64<false,false,true,true,false,false><<<dim3(32,32,32),blk,0,stream>>>(
        qb, kb, nullptr, attn_out, SEQ,SEQ,HD, DIM,DIM,SEQ,
        NH, SD,(long long)HD, SD,(long long)HD, (long long)NH*SS, SS, 0.125f);

    // softmax in place over 65536 rows of 2048 (f32)
    softmax_f32<<<dim3((BBS*NH*SEQ)/4),blk,0,stream>>>(attn_out);

    // ctx1 = probs(f32) @ V_head  (per (b,h): [2048,2048]@[2048,64]) -> cb
    gemm64<true,false,false,false,false,false><<<dim3(1,32,32),blk,0,stream>>>(
        attn_out, vb, nullptr, cb, SEQ,HD,SEQ, SEQ,DIM,DIM,
        NH, (long long)NH*SS, SS, SD,(long long)HD, SD,(long long)HD, 1.f);

    // out projection 1 -> o1 f32
    gemm64<false,true,false,true,false,true><<<dim3(16,64,1),blk,0,stream>>>(cb, wo1, bo1, o1, NT,DIM,DIM, DIM,DIM,DIM, 1, 0,0,0,0,0,0, 1.f);

    // sum = LN(o1+x) + LN(o2+x) -> sumbf + sumf
    add_ln2_kernel<<<dim3(NT),blk,0,stream>>>(o1, o2, x, g1, be1, g2, be2, sumbf, sumf);

    // FFN (hbuf aliases qb..cb; ffo aliases o1 — both dead by now)
    gemm64<false,true,false,false,true,true><<<dim3(64,64,1),blk,0,stream>>>(sumbf, wc1, bc1, hbuf, NT,DFF_,DIM, DIM,DFF_,DFF_, 1, 0,0,0,0,0,0, 1.f);
    gemm64<false,true,false,true,false,true><<<dim3(16,64,1),blk,0,stream>>>(hbuf, wc2, bc2, ffo, NT,DIM,DFF_, DFF_,DIM,DIM, 1, 0,0,0,0,0,0, 1.f);

    // enc = LN(ffn_out + sum)
    final_ln_kernel<<<dim3(NT),blk,0,stream>>>(ffo, sumf, g3, be3, enc_out);
}